// Round 11
// baseline (2465.200 us; speedup 1.0000x reference)
//
#include <hip/hip_runtime.h>
#include <hip/hip_bf16.h>

// LSTM Seq2Seq persistent kernel, fp16 MFMA + fp32 cell state. Round 18:
// r14/r17 structure (wave-role split L0||L1, split flags, 32-slot
// global_load_lds staging, device-scope sc0sc1 sync) with two changes:
// 1) CHUNKED-dispatch XCD heuristic: colg = blk>>4, rowg = blk&15.
//    r17 (neutral FETCH) implies dispatch->XCD is chunked (blk/32), not
//    round-robin: under chunked, both r14 and r17 put all 16 weight
//    slices on every XCD -> 6.4MB > 4MB L2 -> the invariant 522MB/phase
//    L2-miss stream from L3. With colg = blk>>4, XCD x (blocks 32x..+31)
//    hosts only colg {2x,2x+1} = ~800KB -> weights L2-resident.
//    Heuristic only: correctness is mapping-agnostic (all cross-block
//    traffic device-scope sc0sc1).
// 2) s_sleep(1) backoff in the flag poll: r13/r17's multi-ms outlier
//    dispatches are fabric starvation from 256 blocks tight-spinning
//    device-scope loads.

typedef _Float16 half8 __attribute__((ext_vector_type(8)));
typedef _Float16 half4 __attribute__((ext_vector_type(4)));
typedef float floatx4 __attribute__((ext_vector_type(4)));

#define NBLK 256
#define NTHR 512

__device__ __forceinline__ float sigf(float x) { return 1.f / (1.f + __expf(-x)); }
__device__ __forceinline__ float tanhf_(float x) { return 1.f - 2.f / (__expf(2.f * x) + 1.f); }

// Wait until all 16 group flags in f0 >= v0 AND in f1 >= v1.
// Lanes 0-15 poll f0, 16-31 poll f1, 32-63 mirror (lane&31).
__device__ __forceinline__ void fwait2(const unsigned* f0, const unsigned* f1,
                                       unsigned v0, unsigned v1) {
  if (threadIdx.x < 64) {
    int l = threadIdx.x & 31;
    const unsigned* p = (l < 16) ? (f0 + l) : (f1 + (l - 16));
    unsigned tgt = (l < 16) ? v0 : v1;
    for (;;) {
      unsigned f;
      asm volatile("global_load_dword %0, %1, off sc0 sc1\n\t"
                   "s_waitcnt vmcnt(0)" : "=v"(f) : "v"(p) : "memory");
      if (__all(f >= tgt)) break;
      __builtin_amdgcn_s_sleep(1);          // backoff: avoid fabric starvation
    }
  }
  __syncthreads();
}

// Drain own wave's outstanding VMEM (incl. asm stores + lds-loads), then
// block-wide barrier: after this, all waves' stores are at the coherent
// point and all staged LDS data is valid.
__device__ __forceinline__ void drain_sync() {
  asm volatile("s_waitcnt vmcnt(0)" ::: "memory");
  __syncthreads();
}

__device__ __forceinline__ void pubstore(unsigned* p, unsigned v) {
  asm volatile("global_store_dword %0, %1, off sc0 sc1"
               :: "v"(p), "v"(v) : "memory");
}

// ---------------- prep kernel ----------------
__global__ void prep_kernel(
    const float* __restrict__ src,
    const float* __restrict__ eWih0, const float* __restrict__ eWhh0,
    const float* __restrict__ ebih0, const float* __restrict__ ebhh0,
    const float* __restrict__ eWih1, const float* __restrict__ eWhh1,
    const float* __restrict__ ebih1, const float* __restrict__ ebhh1,
    const float* __restrict__ dWih0, const float* __restrict__ dWhh0,
    const float* __restrict__ dbih0, const float* __restrict__ dbhh0,
    const float* __restrict__ dWih1, const float* __restrict__ dWhh1,
    const float* __restrict__ dbih1, const float* __restrict__ dbhh1,
    const float* __restrict__ fc1w, const float* __restrict__ fc1b,
    const float* __restrict__ fc4w, const float* __restrict__ fc4b,
    _Float16* W0e, _Float16* W1e, _Float16* W0d, _Float16* W1d,
    float* bs, _Float16* A1,
    _Float16* Xe, _Float16* Xd, _Float16* Wfc, float* bfc, unsigned* gflags)
{
  const int T = gridDim.x * blockDim.x;
  const int idx = blockIdx.x * blockDim.x + threadIdx.x;

  // L0 weights: row r = [Whh0[r][0..511] | Wih0[r][0..31]], stride 544
  for (int i = idx; i < 2048 * 544; i += T) {
    int r = i / 544, k = i - r * 544;
    W0e[i] = (_Float16)(k < 512 ? eWhh0[r * 512 + k] : eWih0[r * 32 + k - 512]);
    W0d[i] = (_Float16)(k < 512 ? dWhh0[r * 512 + k] : dWih0[r * 32 + k - 512]);
  }
  // L1 weights: row r = [Whh1 (k:0..511 <-> h1) | Wih1 (k:512..1023 <-> h0)]
  for (int i = idx; i < 2048 * 1024; i += T) {
    int r = i >> 10, k = i & 1023;
    W1e[i] = (_Float16)(k < 512 ? eWhh1[r * 512 + k] : eWih1[r * 512 + k - 512]);
    W1d[i] = (_Float16)(k < 512 ? dWhh1[r * 512 + k] : dWih1[r * 512 + k - 512]);
  }
  // combined biases bih+bhh: [b0e | b1e | b0d | b1d]
  for (int i = idx; i < 2048; i += T) {
    bs[i]        = ebih0[i] + ebhh0[i];
    bs[2048 + i] = ebih1[i] + ebhh1[i];
    bs[4096 + i] = dbih0[i] + dbhh0[i];
    bs[6144 + i] = dbih1[i] + dbhh1[i];
  }
  // FC weights: rows 0..31 = fc4w, row 32 = fc1w, rows 33..47 zero
  for (int i = idx; i < 48 * 512; i += T) {
    int r = i >> 9, k = i & 511;
    float v = (r < 32) ? fc4w[r * 512 + k] : (r == 32 ? fc1w[k] : 0.f);
    Wfc[i] = (_Float16)v;
  }
  for (int i = idx; i < 64; i += T)
    bfc[i] = (i < 32) ? fc4b[i] : (i == 32 ? fc1b[0] : 0.f);
  // encoder inputs step-major: Xe[t][b][f] = src[b][t][f]
  for (int i = idx; i < 96 * 512 * 32; i += T) {
    int t = i / (512 * 32); int rem = i - t * 512 * 32; int b = rem >> 5; int f = rem & 31;
    Xe[i] = (_Float16)src[(size_t)b * 96 * 32 + t * 32 + f];
  }
  // decoder x_init = src[:, 95, :]
  for (int i = idx; i < 512 * 32; i += T) {
    int b = i >> 5, f = i & 31;
    Xd[i] = (_Float16)src[(size_t)b * 96 * 32 + 95 * 32 + f];
  }
  // zero h double-buffer [h1 | h0] and barrier flags (ws is 0xAA-poisoned)
  for (int i = idx; i < 2 * 512 * 1024; i += T) A1[i] = (_Float16)0.f;
  for (int i = idx; i < 2048; i += T) gflags[i] = 0u;
}

// ---------------- A staging: global_load_lds, coherent, zero VGPRs --------
// 32 slots (16 col-chunks x 2 row-halves); slot idx = c*2+mt: LDS
// [idx][lane][8 halves], lane = kq*16+m. A role's 4 waves (wq = wv&3)
// issue 8 slots each; lane l supplies the global address, hardware writes
// LDS at slotbase + l*16B. aux = 0x11 = SC0|SC1 (coherent read).
__device__ __forceinline__ void stage_lds(const _Float16* src, int colbase,
                                          _Float16* Ast, int row0, int wq, int lane)
{
#pragma unroll
  for (int i = 0; i < 8; ++i) {
    int idx = wq * 8 + i;                 // slot = c*2+mt, idx in [0,32)
    int c = idx >> 1, mt = idx & 1;
    const _Float16* p = src + (size_t)(row0 + mt * 16 + (lane & 15)) * 1024
                        + colbase + c * 32 + (lane >> 4) * 8;
    _Float16* l = Ast + (size_t)idx * 512;
    __builtin_amdgcn_global_load_lds(
        (const __attribute__((address_space(1))) void*)p,
        (__attribute__((address_space(3))) void*)l, 16, 0, 0x11);
  }
}

// ---------------- GEMM pieces (wave = one gate, 2 mt x 2 nt tiles) ----------
__device__ __forceinline__ void acc_init(floatx4 (&acc)[2][2],
    const float* __restrict__ bsum, int g, int col0, int row_a)
{
#pragma unroll
  for (int nt = 0; nt < 2; ++nt) {
    float b = bsum[g * 512 + col0 + nt * 16 + row_a];
    acc[0][nt] = (floatx4){b, b, b, b};
    acc[1][nt] = (floatx4){b, b, b, b};
  }
}

// wr0/wr1 must already include the per-lane kq*8 K offset.
template <int NCH>
__device__ __forceinline__ void gemm_part(floatx4 (&acc)[2][2],
    const _Float16* Ast, const _Float16* __restrict__ wr0,
    const _Float16* __restrict__ wr1, int koff, int lane)
{
#pragma unroll 8
  for (int c = 0; c < NCH; ++c) {
    half8 a0 = *(const half8*)(Ast + ((c * 2 + 0) * 64 + lane) * 8);
    half8 a1 = *(const half8*)(Ast + ((c * 2 + 1) * 64 + lane) * 8);
    half8 b0 = *(const half8*)(wr0 + koff + c * 32);
    half8 b1 = *(const half8*)(wr1 + koff + c * 32);
    acc[0][0] = __builtin_amdgcn_mfma_f32_16x16x32_f16(a0, b0, acc[0][0], 0, 0, 0);
    acc[1][0] = __builtin_amdgcn_mfma_f32_16x16x32_f16(a1, b0, acc[1][0], 0, 0, 0);
    acc[0][1] = __builtin_amdgcn_mfma_f32_16x16x32_f16(a0, b1, acc[0][1], 0, 0, 0);
    acc[1][1] = __builtin_amdgcn_mfma_f32_16x16x32_f16(a1, b1, acc[1][1], 0, 0, 0);
  }
}

__device__ __forceinline__ void gemm_x(floatx4 (&acc)[2][2],
    const _Float16* __restrict__ X, const _Float16* __restrict__ wr0,
    const _Float16* __restrict__ wr1, int koff, int row0, int lane)
{
  const int row_a = lane & 15, kq = lane >> 4;
  half8 a0 = *(const half8*)(X + (size_t)(row0 + row_a) * 32 + kq * 8);
  half8 a1 = *(const half8*)(X + (size_t)(row0 + 16 + row_a) * 32 + kq * 8);
  half8 b0 = *(const half8*)(wr0 + koff);
  half8 b1 = *(const half8*)(wr1 + koff);
  acc[0][0] = __builtin_amdgcn_mfma_f32_16x16x32_f16(a0, b0, acc[0][0], 0, 0, 0);
  acc[1][0] = __builtin_amdgcn_mfma_f32_16x16x32_f16(a1, b0, acc[1][0], 0, 0, 0);
  acc[0][1] = __builtin_amdgcn_mfma_f32_16x16x32_f16(a0, b1, acc[0][1], 0, 0, 0);
  acc[1][1] = __builtin_amdgcn_mfma_f32_16x16x32_f16(a1, b1, acc[1][1], 0, 0, 0);
}

__device__ __forceinline__ void zwrite(const floatx4 (&acc)[2][2],
    float* Zacc, int g, int lane)
{
  const int row_a = lane & 15, kq = lane >> 4;
#pragma unroll
  for (int mt = 0; mt < 2; ++mt)
#pragma unroll
    for (int nt = 0; nt < 2; ++nt)
#pragma unroll
      for (int j = 0; j < 4; ++j)
        Zacc[g * 1152 + (mt * 16 + kq * 4 + j) * 36 + nt * 16 + row_a] = acc[mt][nt][j];
}

// LSTM pointwise epilogue; one ROLE's 256 threads: tr in [0,256), thread
// owns row r=tr>>3 and 4 cols at (tr&7)*4, cell state in registers.
__device__ __forceinline__ void epi(const float* Zacc, float (&cr)[4],
    _Float16* bufW, int row0, int dcol0, int tr)
{
  int r = tr >> 3, cb = (tr & 7) * 4;
  half4 hv;
#pragma unroll
  for (int k = 0; k < 4; ++k) {
    float iv = Zacc[0 * 1152 + r * 36 + cb + k];
    float fv = Zacc[1 * 1152 + r * 36 + cb + k];
    float gv = Zacc[2 * 1152 + r * 36 + cb + k];
    float ov = Zacc[3 * 1152 + r * 36 + cb + k];
    float cn = sigf(fv) * cr[k] + sigf(iv) * tanhf_(gv);
    cr[k] = cn;
    hv[k] = (_Float16)(sigf(ov) * tanhf_(cn));
  }
  unsigned long long hvu;
  __builtin_memcpy(&hvu, &hv, 8);
  const _Float16* dp = bufW + (size_t)(row0 + r) * 1024 + dcol0 + cb;
  asm volatile("global_store_dwordx2 %0, %1, off sc0 sc1"
               :: "v"(dp), "v"(hvu) : "memory");
}

// ---------------- decoder FC heads (role-H's 4 waves, 6 tiles) -------------
__device__ __forceinline__ void fc_do(const _Float16* Ast,
    const _Float16* __restrict__ Wfc, const float* __restrict__ bfc,
    float* __restrict__ out, _Float16* __restrict__ Xd,
    int row0, int g, int lane, bool wr_out, int d)
{
  const int row_a = lane & 15, kq = lane >> 4;
#pragma unroll
  for (int rep = 0; rep < 2; ++rep) {
    int ft = g + rep * 4;
    if (ft < 6) {
      int mt = ft / 3, nt = ft % 3;
      float b = bfc[nt * 16 + row_a];
      floatx4 acc = (floatx4){b, b, b, b};
      const _Float16* wr = Wfc + (size_t)(nt * 16 + row_a) * 512 + kq * 8;
#pragma unroll 8
      for (int c = 0; c < 16; ++c) {
        half8 a = *(const half8*)(Ast + ((c * 2 + mt) * 64 + lane) * 8);
        half8 bb = *(const half8*)(wr + c * 32);
        acc = __builtin_amdgcn_mfma_f32_16x16x32_f16(a, bb, acc, 0, 0, 0);
      }
      int col = nt * 16 + row_a;
#pragma unroll
      for (int j = 0; j < 4; ++j) {
        int row = row0 + mt * 16 + kq * 4 + j;
        if (col < 32) Xd[row * 32 + col] = (_Float16)acc[j];
        else if (col == 32 && wr_out) out[row * 24 + d] = acc[j];
      }
    }
  }
}

// ---------------- persistent recurrence kernel ----------------
__global__ void __launch_bounds__(NTHR, 1) lstm_main(
    const _Float16* __restrict__ W0e, const _Float16* __restrict__ W1e,
    const _Float16* __restrict__ W0d, const _Float16* __restrict__ W1d,
    const float* __restrict__ bs, _Float16* A1,
    const _Float16* __restrict__ Xe, _Float16* Xd,
    const _Float16* __restrict__ Wfc, const float* __restrict__ bfc,
    float* out, unsigned* gflags)
{
  const int tid = threadIdx.x;
  const int lane = tid & 63, wv = tid >> 6;   // 8 waves
  const int g = wv & 3;                       // gate index within role
  const bool roleL = (wv < 4);                // L: L0 chain; H: L1 chain
  const int blk = (int)blockIdx.x;
  // CHUNKED-dispatch XCD heuristic (perf only; correctness mapping-agnostic):
  // if XCD = blk/32, then XCD x hosts colg {2x,2x+1} only -> ~800KB of
  // weight slices per XCD L2 -> weights L2-resident across phases.
  const int colg = blk >> 4;
  const int rowg = blk & 15;
  const int row0 = rowg * 32, col0 = colg * 32;
  const int row_a = lane & 15;
  const int kq8 = (lane >> 4) * 8;            // per-lane K offset for B frags

  const unsigned* f0r = gflags + rowg * 32;         // group flag0 line
  const unsigned* f1r = gflags + 512 + rowg * 32;   // group flag1 line
  unsigned* f0w = (unsigned*)f0r + colg;
  unsigned* f1w = (unsigned*)f1r + colg;

  __shared__ _Float16 AstA[32 * 64 * 8];      // 32 KB, h0 staging
  __shared__ _Float16 AstB[32 * 64 * 8];      // 32 KB, h1 staging
  __shared__ float Zacc[4 * 32 * 36];         // 18.4 KB gate-acc (L0 / dec)
  __shared__ float Zacc2[4 * 32 * 36];        // 18.4 KB gate-acc (L1 / dec)
  float c0r[4] = {0.f, 0.f, 0.f, 0.f};        // live in role-L threads
  float c1r[4] = {0.f, 0.f, 0.f, 0.f};        // live in role-H threads

  _Float16* bufR = A1;
  _Float16* bufW = A1 + (size_t)512 * 1024;
  unsigned ph = 0;                            // completed-phase counter

  // ---- encoder: phase t = L0(t) [role-L] || L1(t-1) [role-H]; t==96's
  // "L0" is the first decoder L0 (x=x_init, W0d), its L1 is enc L1(95).
  for (int t = 0; t < 97; ++t) {
    const bool dec0 = (t == 96);
    const _Float16* W0 = dec0 ? W0d : W0e;
    const float* bs0 = bs + (dec0 ? 4096 : 0);
    const _Float16* xp = dec0 ? Xd : Xe + (size_t)t * 512 * 32;
    // per-role weight row pointers
    const _Float16* wr0 = roleL
        ? W0  + (size_t)(g * 512 + col0 + row_a) * 544 + kq8
        : W1e + (size_t)(g * 512 + col0 + row_a) * 1024 + kq8;
    const _Float16* wr1 = roleL
        ? W0  + (size_t)(g * 512 + col0 + 16 + row_a) * 544 + kq8
        : W1e + (size_t)(g * 512 + col0 + 16 + row_a) * 1024 + kq8;

    // wait: h0(t-1) fully published (f0>=t), h1(t-2) published (f1>=t)
    fwait2(f0r, f1r, ph, ph);
    if (roleL) stage_lds(bufR, 512, AstA, row0, g, lane);   // h0(t-1)
    else       stage_lds(bufR, 0,   AstB, row0, g, lane);   // h1(t-2)

    floatx4 acc[2][2];
    if (roleL) {
      acc_init(acc, bs0, g, col0, row_a);
      gemm_x(acc, xp, wr0, wr1, 512, row0, lane);           // x-part overlap
    } else if (t >= 1) {
      acc_init(acc, bs + 2048, g, col0, row_a);
    }
    drain_sync();                    // AstA+AstB valid for all waves
    if (roleL) {
      gemm_part<16>(acc, AstA, wr0, wr1, 0, lane);
      zwrite(acc, Zacc, g, lane);
    } else if (t >= 1) {
      gemm_part<16>(acc, AstA, wr0, wr1, 512, lane);        // h0 -> W1 k512
      gemm_part<16>(acc, AstB, wr0, wr1, 0, lane);          // h1 -> W1 k0
      zwrite(acc, Zacc2, g, lane);
    }
    __syncthreads();                 // Zacc/Zacc2 valid
    if (roleL)       epi(Zacc,  c0r, bufW, row0, 512 + col0, tid);       // h0(t)
    else if (t >= 1) epi(Zacc2, c1r, bufW, row0, col0, tid - 256);       // h1(t-1)
    drain_sync();                    // all epi stores at coherent point
    ph++;
    if (tid == 0)  pubstore(f0w, ph);
    if (tid == 64) pubstore(f1w, ph);
    _Float16* tmp = bufR; bufR = bufW; bufW = tmp;
  }
  // ph == 97; bufR = [h1(95) | h0(0)]

  // decoder weight pointers (constant)
  const _Float16* w1r0 = W1d + (size_t)(g * 512 + col0 + row_a) * 1024 + kq8;
  const _Float16* w1r1 = W1d + (size_t)(g * 512 + col0 + 16 + row_a) * 1024 + kq8;
  const _Float16* w0r0 = W0d + (size_t)(g * 512 + col0 + row_a) * 544 + kq8;
  const _Float16* w0r1 = W0d + (size_t)(g * 512 + col0 + 16 + row_a) * 544 + kq8;

  // ---- decoder: bufR = [h1(d-1) | h0(d)]
  for (int d = 0; d < 24; ++d) {
    // Phase A: h1(d) = L1d([h1(d-1)|h0(d)])  [role-H computes]
    {
      // h1(d-1) on f0 (=97+d), h0(d) on f1 (=97+d)
      fwait2(f0r, f1r, 97 + d, 97 + d);
      if (roleL) stage_lds(bufR, 512, AstA, row0, g, lane); // h0(d)
      else       stage_lds(bufR, 0,   AstB, row0, g, lane); // h1(d-1)
      floatx4 acc[2][2];
      if (!roleL) acc_init(acc, bs + 6144, g, col0, row_a);
      drain_sync();
      if (!roleL) {
        gemm_part<16>(acc, AstA, w1r0, w1r1, 512, lane);
        gemm_part<16>(acc, AstB, w1r0, w1r1, 0, lane);
        zwrite(acc, Zacc, g, lane);
      }
      __syncthreads();
      if (!roleL) epi(Zacc, c1r, bufW, row0, col0, tid - 256);  // h1(d)
      drain_sync();
      if (tid == 0) pubstore(f0w, 98 + d);
    }

    // Phase B: FC heads on h1(d) [role-H], L0d(d+1) [role-L]
    {
      fwait2(f0r, f1r, 98 + d, 0);        // h1(d) published by all peers
      if (roleL) stage_lds(bufW, 0, AstA, row0, g, lane);   // h1(d)
      else if (d < 23) stage_lds(bufR, 512, AstB, row0, g, lane); // h0(d)
      floatx4 acc[2][2];
      if (roleL && d < 23) acc_init(acc, bs + 4096, g, col0, row_a);
      drain_sync();
      if (!roleL) fc_do(AstA, Wfc, bfc, out, Xd, row0, g, lane, colg == 0, d);
      else if (d < 23) gemm_part<16>(acc, AstB, w0r0, w0r1, 0, lane); // h-part
      __syncthreads();                    // Xd writes visible
      if (roleL && d < 23) {
        gemm_x(acc, Xd, w0r0, w0r1, 512, row0, lane);
        zwrite(acc, Zacc2, g, lane);
      }
      __syncthreads();
      if (roleL && d < 23) epi(Zacc2, c0r, bufW, row0, 512 + col0, tid); // h0(d+1)
      drain_sync();
      if (d < 23 && tid == 64) pubstore(f1w, 98 + d);
    }
    _Float16* tmp = bufR; bufR = bufW; bufW = tmp;
  }
}

// ---------------- host ----------------
extern "C" void kernel_launch(void* const* d_in, const int* in_sizes, int n_in,
                              void* d_out, int out_size, void* d_ws, size_t ws_size,
                              hipStream_t stream)
{
  const int base = (in_sizes[2] == 1) ? 3 : 2;
  const float* src   = (const float*)d_in[0];
  const float* eWih0 = (const float*)d_in[base + 0];
  const float* eWhh0 = (const float*)d_in[base + 1];
  const float* ebih0 = (const float*)d_in[base + 2];
  const float* ebhh0 = (const float*)d_in[base + 3];
  const float* eWih1 = (const float*)d_in[base + 4];
  const float* eWhh1 = (const float*)d_in[base + 5];
  const float* ebih1 = (const float*)d_in[base + 6];
  const float* ebhh1 = (const float*)d_in[base + 7];
  const float* dWih0 = (const float*)d_in[base + 8];
  const float* dWhh0 = (const float*)d_in[base + 9];
  const float* dbih0 = (const float*)d_in[base + 10];
  const float* dbhh0 = (const float*)d_in[base + 11];
  const float* dWih1 = (const float*)d_in[base + 12];
  const float* dWhh1 = (const float*)d_in[base + 13];
  const float* dbih1 = (const float*)d_in[base + 14];
  const float* dbhh1 = (const float*)d_in[base + 15];
  const float* fc1w  = (const float*)d_in[base + 16];
  const float* fc1b  = (const float*)d_in[base + 17];
  const float* fc4w  = (const float*)d_in[base + 18];
  const float* fc4b  = (const float*)d_in[base + 19];

  char* p = (char*)d_ws;
  _Float16* W0e = (_Float16*)p; p += 2048 * 544 * 2;
  _Float16* W1e = (_Float16*)p; p += 2048 * 1024 * 2;
  _Float16* W0d = (_Float16*)p; p += 2048 * 544 * 2;
  _Float16* W1d = (_Float16*)p; p += 2048 * 1024 * 2;
  float*    bsv = (float*)p;    p += 8192 * 4;
  _Float16* A1  = (_Float16*)p; p += 2 * 512 * 1024 * 2;
  _Float16* Xe  = (_Float16*)p; p += 96 * 512 * 32 * 2;
  _Float16* Xd  = (_Float16*)p; p += 512 * 32 * 2;
  _Float16* Wfc = (_Float16*)p; p += 48 * 512 * 2;
  float*    bfc = (float*)p;    p += 64 * 4;
  unsigned* gflags = (unsigned*)p; p += 2048 * 4;

  hipLaunchKernelGGL(prep_kernel, dim3(1024), dim3(256), 0, stream,
      src, eWih0, eWhh0, ebih0, ebhh0, eWih1, eWhh1, ebih1, ebhh1,
      dWih0, dWhh0, dbih0, dbhh0, dWih1, dWhh1, dbih1, dbhh1,
      fc1w, fc1b, fc4w, fc4b,
      W0e, W1e, W0d, W1d, bsv, A1, Xe, Xd, Wfc, bfc, gflags);

  float* out = (float*)d_out;
  void* kargs[] = { &W0e, &W1e, &W0d, &W1d, &bsv, &A1,
                    &Xe, &Xd, &Wfc, &bfc, &out, &gflags };
  hipLaunchCooperativeKernel(reinterpret_cast<void*>(lstm_main),
                             dim3(NBLK), dim3(NTHR), kargs, 0, stream);
}

// Round 12
// 1692.047 us; speedup vs baseline: 1.4569x; 1.4569x over previous
//
#include <hip/hip_runtime.h>
#include <hip/hip_bf16.h>

// LSTM Seq2Seq persistent kernel, fp16 MFMA + fp32 cell state. Round 19:
// r14 structure + mapping (wave-role split L0||L1, split flags, 32-slot
// global_load_lds staging, device-scope sc0sc1, rowg=blk>>4/colg=blk&15;
// r18's remap reverted -- its 6x FETCH explosion + r17's neutrality imply
// round-robin dispatch, under which r14's mapping already gives each XCD
// only 2 weight slices) with REGISTER-RESIDENT WEIGHTS:
// - B fragments are loop-invariant across the 97 encoder phases. Both
//   roles cache into the SAME arrays (shared static live range -> shared
//   registers): role-L all 17 W0e chunks (h 0..15 + x), role-H the k=512
//   half of W1e (16 chunks). +136 VGPR (108 -> ~244 <= 256, still 2
//   waves/SIMD). Encoder GEMMs become LDS-read + MFMA with ZERO B-load
//   latency; role-H streams only its k=0 half from L2.
// - t=96: role-L refills cache with W0d. After encoder: role-H refills
//   with W1d k=512 half -> decoder phases get the same treatment.
// - full #pragma unroll so all cache indices are compile-time (no scratch).
// Keeps r18's s_sleep(1) poll backoff (outlier mitigation).

typedef _Float16 half8 __attribute__((ext_vector_type(8)));
typedef _Float16 half4 __attribute__((ext_vector_type(4)));
typedef float floatx4 __attribute__((ext_vector_type(4)));

#define NBLK 256
#define NTHR 512

__device__ __forceinline__ float sigf(float x) { return 1.f / (1.f + __expf(-x)); }
__device__ __forceinline__ float tanhf_(float x) { return 1.f - 2.f / (__expf(2.f * x) + 1.f); }

// Wait until all 16 group flags in f0 >= v0 AND in f1 >= v1.
__device__ __forceinline__ void fwait2(const unsigned* f0, const unsigned* f1,
                                       unsigned v0, unsigned v1) {
  if (threadIdx.x < 64) {
    int l = threadIdx.x & 31;
    const unsigned* p = (l < 16) ? (f0 + l) : (f1 + (l - 16));
    unsigned tgt = (l < 16) ? v0 : v1;
    for (;;) {
      unsigned f;
      asm volatile("global_load_dword %0, %1, off sc0 sc1\n\t"
                   "s_waitcnt vmcnt(0)" : "=v"(f) : "v"(p) : "memory");
      if (__all(f >= tgt)) break;
      __builtin_amdgcn_s_sleep(1);          // backoff: avoid fabric starvation
    }
  }
  __syncthreads();
}

__device__ __forceinline__ void drain_sync() {
  asm volatile("s_waitcnt vmcnt(0)" ::: "memory");
  __syncthreads();
}

__device__ __forceinline__ void pubstore(unsigned* p, unsigned v) {
  asm volatile("global_store_dword %0, %1, off sc0 sc1"
               :: "v"(p), "v"(v) : "memory");
}

// ---------------- prep kernel ----------------
__global__ void prep_kernel(
    const float* __restrict__ src,
    const float* __restrict__ eWih0, const float* __restrict__ eWhh0,
    const float* __restrict__ ebih0, const float* __restrict__ ebhh0,
    const float* __restrict__ eWih1, const float* __restrict__ eWhh1,
    const float* __restrict__ ebih1, const float* __restrict__ ebhh1,
    const float* __restrict__ dWih0, const float* __restrict__ dWhh0,
    const float* __restrict__ dbih0, const float* __restrict__ dbhh0,
    const float* __restrict__ dWih1, const float* __restrict__ dWhh1,
    const float* __restrict__ dbih1, const float* __restrict__ dbhh1,
    const float* __restrict__ fc1w, const float* __restrict__ fc1b,
    const float* __restrict__ fc4w, const float* __restrict__ fc4b,
    _Float16* W0e, _Float16* W1e, _Float16* W0d, _Float16* W1d,
    float* bs, _Float16* A1,
    _Float16* Xe, _Float16* Xd, _Float16* Wfc, float* bfc, unsigned* gflags)
{
  const int T = gridDim.x * blockDim.x;
  const int idx = blockIdx.x * blockDim.x + threadIdx.x;

  // L0 weights: row r = [Whh0[r][0..511] | Wih0[r][0..31]], stride 544
  for (int i = idx; i < 2048 * 544; i += T) {
    int r = i / 544, k = i - r * 544;
    W0e[i] = (_Float16)(k < 512 ? eWhh0[r * 512 + k] : eWih0[r * 32 + k - 512]);
    W0d[i] = (_Float16)(k < 512 ? dWhh0[r * 512 + k] : dWih0[r * 32 + k - 512]);
  }
  // L1 weights: row r = [Whh1 (k:0..511 <-> h1) | Wih1 (k:512..1023 <-> h0)]
  for (int i = idx; i < 2048 * 1024; i += T) {
    int r = i >> 10, k = i & 1023;
    W1e[i] = (_Float16)(k < 512 ? eWhh1[r * 512 + k] : eWih1[r * 512 + k - 512]);
    W1d[i] = (_Float16)(k < 512 ? dWhh1[r * 512 + k] : dWih1[r * 512 + k - 512]);
  }
  // combined biases bih+bhh: [b0e | b1e | b0d | b1d]
  for (int i = idx; i < 2048; i += T) {
    bs[i]        = ebih0[i] + ebhh0[i];
    bs[2048 + i] = ebih1[i] + ebhh1[i];
    bs[4096 + i] = dbih0[i] + dbhh0[i];
    bs[6144 + i] = dbih1[i] + dbhh1[i];
  }
  // FC weights: rows 0..31 = fc4w, row 32 = fc1w, rows 33..47 zero
  for (int i = idx; i < 48 * 512; i += T) {
    int r = i >> 9, k = i & 511;
    float v = (r < 32) ? fc4w[r * 512 + k] : (r == 32 ? fc1w[k] : 0.f);
    Wfc[i] = (_Float16)v;
  }
  for (int i = idx; i < 64; i += T)
    bfc[i] = (i < 32) ? fc4b[i] : (i == 32 ? fc1b[0] : 0.f);
  // encoder inputs step-major: Xe[t][b][f] = src[b][t][f]
  for (int i = idx; i < 96 * 512 * 32; i += T) {
    int t = i / (512 * 32); int rem = i - t * 512 * 32; int b = rem >> 5; int f = rem & 31;
    Xe[i] = (_Float16)src[(size_t)b * 96 * 32 + t * 32 + f];
  }
  // decoder x_init = src[:, 95, :]
  for (int i = idx; i < 512 * 32; i += T) {
    int b = i >> 5, f = i & 31;
    Xd[i] = (_Float16)src[(size_t)b * 96 * 32 + 95 * 32 + f];
  }
  // zero h double-buffer [h1 | h0] and barrier flags (ws is 0xAA-poisoned)
  for (int i = idx; i < 2 * 512 * 1024; i += T) A1[i] = (_Float16)0.f;
  for (int i = idx; i < 2048; i += T) gflags[i] = 0u;
}

// ---------------- A staging: global_load_lds, coherent, zero VGPRs --------
__device__ __forceinline__ void stage_lds(const _Float16* src, int colbase,
                                          _Float16* Ast, int row0, int wq, int lane)
{
#pragma unroll
  for (int i = 0; i < 8; ++i) {
    int idx = wq * 8 + i;                 // slot = c*2+mt, idx in [0,32)
    int c = idx >> 1, mt = idx & 1;
    const _Float16* p = src + (size_t)(row0 + mt * 16 + (lane & 15)) * 1024
                        + colbase + c * 32 + (lane >> 4) * 8;
    _Float16* l = Ast + (size_t)idx * 512;
    __builtin_amdgcn_global_load_lds(
        (const __attribute__((address_space(1))) void*)p,
        (__attribute__((address_space(3))) void*)l, 16, 0, 0x11);
  }
}

// ---------------- GEMM pieces (wave = one gate, 2 mt x 2 nt tiles) ----------
__device__ __forceinline__ void acc_init(floatx4 (&acc)[2][2],
    const float* __restrict__ bsum, int g, int col0, int row_a)
{
#pragma unroll
  for (int nt = 0; nt < 2; ++nt) {
    float b = bsum[g * 512 + col0 + nt * 16 + row_a];
    acc[0][nt] = (floatx4){b, b, b, b};
    acc[1][nt] = (floatx4){b, b, b, b};
  }
}

// streamed-B variant (wr0/wr1 include per-lane kq*8 K offset)
template <int NCH>
__device__ __forceinline__ void gemm_part(floatx4 (&acc)[2][2],
    const _Float16* Ast, const _Float16* __restrict__ wr0,
    const _Float16* __restrict__ wr1, int koff, int lane)
{
#pragma unroll 8
  for (int c = 0; c < NCH; ++c) {
    half8 a0 = *(const half8*)(Ast + ((c * 2 + 0) * 64 + lane) * 8);
    half8 a1 = *(const half8*)(Ast + ((c * 2 + 1) * 64 + lane) * 8);
    half8 b0 = *(const half8*)(wr0 + koff + c * 32);
    half8 b1 = *(const half8*)(wr1 + koff + c * 32);
    acc[0][0] = __builtin_amdgcn_mfma_f32_16x16x32_f16(a0, b0, acc[0][0], 0, 0, 0);
    acc[1][0] = __builtin_amdgcn_mfma_f32_16x16x32_f16(a1, b0, acc[1][0], 0, 0, 0);
    acc[0][1] = __builtin_amdgcn_mfma_f32_16x16x32_f16(a0, b1, acc[0][1], 0, 0, 0);
    acc[1][1] = __builtin_amdgcn_mfma_f32_16x16x32_f16(a1, b1, acc[1][1], 0, 0, 0);
  }
}

// cached-B variant: B frags live in registers, full unroll (const indices)
__device__ __forceinline__ void gemm_partC(floatx4 (&acc)[2][2],
    const _Float16* Ast, const half8 (&b0c)[16], const half8 (&b1c)[16], int lane)
{
#pragma unroll
  for (int c = 0; c < 16; ++c) {
    half8 a0 = *(const half8*)(Ast + ((c * 2 + 0) * 64 + lane) * 8);
    half8 a1 = *(const half8*)(Ast + ((c * 2 + 1) * 64 + lane) * 8);
    acc[0][0] = __builtin_amdgcn_mfma_f32_16x16x32_f16(a0, b0c[c], acc[0][0], 0, 0, 0);
    acc[1][0] = __builtin_amdgcn_mfma_f32_16x16x32_f16(a1, b0c[c], acc[1][0], 0, 0, 0);
    acc[0][1] = __builtin_amdgcn_mfma_f32_16x16x32_f16(a0, b1c[c], acc[0][1], 0, 0, 0);
    acc[1][1] = __builtin_amdgcn_mfma_f32_16x16x32_f16(a1, b1c[c], acc[1][1], 0, 0, 0);
  }
}

__device__ __forceinline__ void gemm_xC(floatx4 (&acc)[2][2],
    const _Float16* __restrict__ X, half8 b0, half8 b1, int row0, int lane)
{
  const int row_a = lane & 15, kq = lane >> 4;
  half8 a0 = *(const half8*)(X + (size_t)(row0 + row_a) * 32 + kq * 8);
  half8 a1 = *(const half8*)(X + (size_t)(row0 + 16 + row_a) * 32 + kq * 8);
  acc[0][0] = __builtin_amdgcn_mfma_f32_16x16x32_f16(a0, b0, acc[0][0], 0, 0, 0);
  acc[1][0] = __builtin_amdgcn_mfma_f32_16x16x32_f16(a1, b0, acc[1][0], 0, 0, 0);
  acc[0][1] = __builtin_amdgcn_mfma_f32_16x16x32_f16(a0, b1, acc[0][1], 0, 0, 0);
  acc[1][1] = __builtin_amdgcn_mfma_f32_16x16x32_f16(a1, b1, acc[1][1], 0, 0, 0);
}

// fill the shared register B-cache (16 chunks at koff)
__device__ __forceinline__ void fill_bc(half8 (&b0c)[16], half8 (&b1c)[16],
    const _Float16* __restrict__ wr0, const _Float16* __restrict__ wr1, int koff)
{
#pragma unroll
  for (int c = 0; c < 16; ++c) {
    b0c[c] = *(const half8*)(wr0 + koff + c * 32);
    b1c[c] = *(const half8*)(wr1 + koff + c * 32);
  }
}

__device__ __forceinline__ void zwrite(const floatx4 (&acc)[2][2],
    float* Zacc, int g, int lane)
{
  const int row_a = lane & 15, kq = lane >> 4;
#pragma unroll
  for (int mt = 0; mt < 2; ++mt)
#pragma unroll
    for (int nt = 0; nt < 2; ++nt)
#pragma unroll
      for (int j = 0; j < 4; ++j)
        Zacc[g * 1152 + (mt * 16 + kq * 4 + j) * 36 + nt * 16 + row_a] = acc[mt][nt][j];
}

// LSTM pointwise epilogue; one ROLE's 256 threads.
__device__ __forceinline__ void epi(const float* Zacc, float (&cr)[4],
    _Float16* bufW, int row0, int dcol0, int tr)
{
  int r = tr >> 3, cb = (tr & 7) * 4;
  half4 hv;
#pragma unroll
  for (int k = 0; k < 4; ++k) {
    float iv = Zacc[0 * 1152 + r * 36 + cb + k];
    float fv = Zacc[1 * 1152 + r * 36 + cb + k];
    float gv = Zacc[2 * 1152 + r * 36 + cb + k];
    float ov = Zacc[3 * 1152 + r * 36 + cb + k];
    float cn = sigf(fv) * cr[k] + sigf(iv) * tanhf_(gv);
    cr[k] = cn;
    hv[k] = (_Float16)(sigf(ov) * tanhf_(cn));
  }
  unsigned long long hvu;
  __builtin_memcpy(&hvu, &hv, 8);
  const _Float16* dp = bufW + (size_t)(row0 + r) * 1024 + dcol0 + cb;
  asm volatile("global_store_dwordx2 %0, %1, off sc0 sc1"
               :: "v"(dp), "v"(hvu) : "memory");
}

// ---------------- decoder FC heads (role-H's 4 waves, 6 tiles) -------------
__device__ __forceinline__ void fc_do(const _Float16* Ast,
    const _Float16* __restrict__ Wfc, const float* __restrict__ bfc,
    float* __restrict__ out, _Float16* __restrict__ Xd,
    int row0, int g, int lane, bool wr_out, int d)
{
  const int row_a = lane & 15, kq = lane >> 4;
#pragma unroll
  for (int rep = 0; rep < 2; ++rep) {
    int ft = g + rep * 4;
    if (ft < 6) {
      int mt = ft / 3, nt = ft % 3;
      float b = bfc[nt * 16 + row_a];
      floatx4 acc = (floatx4){b, b, b, b};
      const _Float16* wr = Wfc + (size_t)(nt * 16 + row_a) * 512 + kq * 8;
#pragma unroll 8
      for (int c = 0; c < 16; ++c) {
        half8 a = *(const half8*)(Ast + ((c * 2 + mt) * 64 + lane) * 8);
        half8 bb = *(const half8*)(wr + c * 32);
        acc = __builtin_amdgcn_mfma_f32_16x16x32_f16(a, bb, acc, 0, 0, 0);
      }
      int col = nt * 16 + row_a;
#pragma unroll
      for (int j = 0; j < 4; ++j) {
        int row = row0 + mt * 16 + kq * 4 + j;
        if (col < 32) Xd[row * 32 + col] = (_Float16)acc[j];
        else if (col == 32 && wr_out) out[row * 24 + d] = acc[j];
      }
    }
  }
}

// ---------------- persistent recurrence kernel ----------------
__global__ void __launch_bounds__(NTHR, 1) lstm_main(
    const _Float16* __restrict__ W0e, const _Float16* __restrict__ W1e,
    const _Float16* __restrict__ W0d, const _Float16* __restrict__ W1d,
    const float* __restrict__ bs, _Float16* A1,
    const _Float16* __restrict__ Xe, _Float16* Xd,
    const _Float16* __restrict__ Wfc, const float* __restrict__ bfc,
    float* out, unsigned* gflags)
{
  const int tid = threadIdx.x;
  const int lane = tid & 63, wv = tid >> 6;   // 8 waves
  const int g = wv & 3;                       // gate index within role
  const bool roleL = (wv < 4);                // L: L0 chain; H: L1 chain
  const int blk = (int)blockIdx.x;
  const int rowg = blk >> 4, colg = blk & 15; // r14 mapping (best known)
  const int row0 = rowg * 32, col0 = colg * 32;
  const int row_a = lane & 15;
  const int kq8 = (lane >> 4) * 8;            // per-lane K offset for B frags

  const unsigned* f0r = gflags + rowg * 32;         // group flag0 line
  const unsigned* f1r = gflags + 512 + rowg * 32;   // group flag1 line
  unsigned* f0w = (unsigned*)f0r + colg;
  unsigned* f1w = (unsigned*)f1r + colg;

  __shared__ _Float16 AstA[32 * 64 * 8];      // 32 KB, h0 staging
  __shared__ _Float16 AstB[32 * 64 * 8];      // 32 KB, h1 staging
  __shared__ float Zacc[4 * 32 * 36];         // 18.4 KB gate-acc (L0 / dec)
  __shared__ float Zacc2[4 * 32 * 36];        // 18.4 KB gate-acc (L1 / dec)
  float c0r[4] = {0.f, 0.f, 0.f, 0.f};        // live in role-L threads
  float c1r[4] = {0.f, 0.f, 0.f, 0.f};        // live in role-H threads

  // ---- shared-role register B-cache (+136 VGPR; shared live range) ----
  half8 bc0[16], bc1[16];                     // role-L: W0e h-chunks; role-H: W1e k512 half
  half8 bx0 = {}, bx1 = {};                   // role-L only: x chunk (koff 512)
  // streamed pointers (role-H k=0 half; loop-invariant)
  const _Float16* w1s0 = W1e + (size_t)(g * 512 + col0 + row_a) * 1024 + kq8;
  const _Float16* w1s1 = W1e + (size_t)(g * 512 + col0 + 16 + row_a) * 1024 + kq8;
  if (roleL) {
    const _Float16* wr0 = W0e + (size_t)(g * 512 + col0 + row_a) * 544 + kq8;
    const _Float16* wr1 = W0e + (size_t)(g * 512 + col0 + 16 + row_a) * 544 + kq8;
    fill_bc(bc0, bc1, wr0, wr1, 0);
    bx0 = *(const half8*)(wr0 + 512);
    bx1 = *(const half8*)(wr1 + 512);
  } else {
    fill_bc(bc0, bc1, w1s0, w1s1, 512);       // k512 half (h0 part)
  }

  _Float16* bufR = A1;
  _Float16* bufW = A1 + (size_t)512 * 1024;
  unsigned ph = 0;                            // completed-phase counter

  // ---- encoder: phase t = L0(t) [role-L] || L1(t-1) [role-H]; t==96's
  // "L0" is the first decoder L0 (x=x_init, W0d), its L1 is enc L1(95).
  for (int t = 0; t < 97; ++t) {
    const bool dec0 = (t == 96);
    const float* bs0 = bs + (dec0 ? 4096 : 0);
    const _Float16* xp = dec0 ? Xd : Xe + (size_t)t * 512 * 32;
    if (dec0 && roleL) {                      // refill cache with W0d
      const _Float16* wr0 = W0d + (size_t)(g * 512 + col0 + row_a) * 544 + kq8;
      const _Float16* wr1 = W0d + (size_t)(g * 512 + col0 + 16 + row_a) * 544 + kq8;
      fill_bc(bc0, bc1, wr0, wr1, 0);
      bx0 = *(const half8*)(wr0 + 512);
      bx1 = *(const half8*)(wr1 + 512);
    }

    // wait: h0(t-1) fully published (f0>=t), h1(t-2) published (f1>=t)
    fwait2(f0r, f1r, ph, ph);
    if (roleL) stage_lds(bufR, 512, AstA, row0, g, lane);   // h0(t-1)
    else       stage_lds(bufR, 0,   AstB, row0, g, lane);   // h1(t-2)

    floatx4 acc[2][2];
    if (roleL) {
      acc_init(acc, bs0, g, col0, row_a);
      gemm_xC(acc, xp, bx0, bx1, row0, lane);               // x-part overlap
    } else if (t >= 1) {
      acc_init(acc, bs + 2048, g, col0, row_a);
    }
    drain_sync();                    // AstA+AstB valid for all waves
    if (roleL) {
      gemm_partC(acc, AstA, bc0, bc1, lane);                // cached W0 h-part
      zwrite(acc, Zacc, g, lane);
    } else if (t >= 1) {
      gemm_partC(acc, AstA, bc0, bc1, lane);                // cached k512 (h0)
      gemm_part<16>(acc, AstB, w1s0, w1s1, 0, lane);        // streamed k0 (h1)
      zwrite(acc, Zacc2, g, lane);
    }
    __syncthreads();                 // Zacc/Zacc2 valid
    if (roleL)       epi(Zacc,  c0r, bufW, row0, 512 + col0, tid);       // h0(t)
    else if (t >= 1) epi(Zacc2, c1r, bufW, row0, col0, tid - 256);       // h1(t-1)
    drain_sync();                    // all epi stores at coherent point
    ph++;
    if (tid == 0)  pubstore(f0w, ph);
    if (tid == 64) pubstore(f1w, ph);
    _Float16* tmp = bufR; bufR = bufW; bufW = tmp;
  }
  // ph == 97; bufR = [h1(95) | h0(0)]

  // decoder streamed pointers (role-H k=0 half of W1d)
  const _Float16* w1r0 = W1d + (size_t)(g * 512 + col0 + row_a) * 1024 + kq8;
  const _Float16* w1r1 = W1d + (size_t)(g * 512 + col0 + 16 + row_a) * 1024 + kq8;
  if (!roleL) fill_bc(bc0, bc1, w1r0, w1r1, 512);   // cache W1d k512 half
  // (role-L cache already holds W0d from t=96)

  // ---- decoder: bufR = [h1(d-1) | h0(d)]
  for (int d = 0; d < 24; ++d) {
    // Phase A: h1(d) = L1d([h1(d-1)|h0(d)])  [role-H computes]
    {
      fwait2(f0r, f1r, 97 + d, 97 + d);
      if (roleL) stage_lds(bufR, 512, AstA, row0, g, lane); // h0(d)
      else       stage_lds(bufR, 0,   AstB, row0, g, lane); // h1(d-1)
      floatx4 acc[2][2];
      if (!roleL) acc_init(acc, bs + 6144, g, col0, row_a);
      drain_sync();
      if (!roleL) {
        gemm_partC(acc, AstA, bc0, bc1, lane);              // cached k512 (h0)
        gemm_part<16>(acc, AstB, w1r0, w1r1, 0, lane);      // streamed k0 (h1)
        zwrite(acc, Zacc, g, lane);
      }
      __syncthreads();
      if (!roleL) epi(Zacc, c1r, bufW, row0, col0, tid - 256);  // h1(d)
      drain_sync();
      if (tid == 0) pubstore(f0w, 98 + d);
    }

    // Phase B: FC heads on h1(d) [role-H], L0d(d+1) [role-L]
    {
      fwait2(f0r, f1r, 98 + d, 0);        // h1(d) published by all peers
      if (roleL) stage_lds(bufW, 0, AstA, row0, g, lane);   // h1(d)
      else if (d < 23) stage_lds(bufR, 512, AstB, row0, g, lane); // h0(d)
      floatx4 acc[2][2];
      if (roleL && d < 23) acc_init(acc, bs + 4096, g, col0, row_a);
      drain_sync();
      if (!roleL) fc_do(AstA, Wfc, bfc, out, Xd, row0, g, lane, colg == 0, d);
      else if (d < 23) gemm_partC(acc, AstB, bc0, bc1, lane);  // cached W0d h-part
      __syncthreads();                    // Xd writes visible
      if (roleL && d < 23) {
        gemm_xC(acc, Xd, bx0, bx1, row0, lane);
        zwrite(acc, Zacc2, g, lane);
      }
      __syncthreads();
      if (roleL && d < 23) epi(Zacc2, c0r, bufW, row0, 512 + col0, tid); // h0(d+1)
      drain_sync();
      if (d < 23 && tid == 64) pubstore(f1w, 98 + d);
    }
    _Float16* tmp = bufR; bufR = bufW; bufW = tmp;
  }
}

// ---------------- host ----------------
extern "C" void kernel_launch(void* const* d_in, const int* in_sizes, int n_in,
                              void* d_out, int out_size, void* d_ws, size_t ws_size,
                              hipStream_t stream)
{
  const int base = (in_sizes[2] == 1) ? 3 : 2;
  const float* src   = (const float*)d_in[0];
  const float* eWih0 = (const float*)d_in[base + 0];
  const float* eWhh0 = (const float*)d_in[base + 1];
  const float* ebih0 = (const float*)d_in[base + 2];
  const float* ebhh0 = (const float*)d_in[base + 3];
  const float* eWih1 = (const float*)d_in[base + 4];
  const float* eWhh1 = (const float*)d_in[base + 5];
  const float* ebih1 = (const float*)d_in[base + 6];
  const float* ebhh1 = (const float*)d_in[base + 7];
  const float* dWih0 = (const float*)d_in[base + 8];
  const float* dWhh0 = (const float*)d_in[base + 9];
  const float* dbih0 = (const float*)d_in[base + 10];
  const float* dbhh0 = (const float*)d_in[base + 11];
  const float* dWih1 = (const float*)d_in[base + 12];
  const float* dWhh1 = (const float*)d_in[base + 13];
  const float* dbih1 = (const float*)d_in[base + 14];
  const float* dbhh1 = (const float*)d_in[base + 15];
  const float* fc1w  = (const float*)d_in[base + 16];
  const float* fc1b  = (const float*)d_in[base + 17];
  const float* fc4w  = (const float*)d_in[base + 18];
  const float* fc4b  = (const float*)d_in[base + 19];

  char* p = (char*)d_ws;
  _Float16* W0e = (_Float16*)p; p += 2048 * 544 * 2;
  _Float16* W1e = (_Float16*)p; p += 2048 * 1024 * 2;
  _Float16* W0d = (_Float16*)p; p += 2048 * 544 * 2;
  _Float16* W1d = (_Float16*)p; p += 2048 * 1024 * 2;
  float*    bsv = (float*)p;    p += 8192 * 4;
  _Float16* A1  = (_Float16*)p; p += 2 * 512 * 1024 * 2;
  _Float16* Xe  = (_Float16*)p; p += 96 * 512 * 32 * 2;
  _Float16* Xd  = (_Float16*)p; p += 512 * 32 * 2;
  _Float16* Wfc = (_Float16*)p; p += 48 * 512 * 2;
  float*    bfc = (float*)p;    p += 64 * 4;
  unsigned* gflags = (unsigned*)p; p += 2048 * 4;

  hipLaunchKernelGGL(prep_kernel, dim3(1024), dim3(256), 0, stream,
      src, eWih0, eWhh0, ebih0, ebhh0, eWih1, eWhh1, ebih1, ebhh1,
      dWih0, dWhh0, dbih0, dbhh0, dWih1, dWhh1, dbih1, dbhh1,
      fc1w, fc1b, fc4w, fc4b,
      W0e, W1e, W0d, W1d, bsv, A1, Xe, Xd, Wfc, bfc, gflags);

  float* out = (float*)d_out;
  void* kargs[] = { &W0e, &W1e, &W0d, &W1d, &bsv, &A1,
                    &Xe, &Xd, &Wfc, &bfc, &out, &gflags };
  hipLaunchCooperativeKernel(reinterpret_cast<void*>(lstm_main),
                             dim3(NBLK), dim3(NTHR), kargs, 0, stream);
}